// Round 5
// baseline (66.963 us; speedup 1.0000x reference)
//
#include <hip/hip_runtime.h>

#define CF 2048
#define TT 64
#define TP 65
#define KK 16
#define SS 4
#define EE 64
#define BB 2
#define DT_CONST 0.005f

// ws layout (floats)
#define PART_OFF 0        // gram partials [64 blocks][136]
#define WK_OFF   8704     // wk [2][64][16] = 2048

// ---------------- kernel A: windowed Gram, scratch-free ----------------
// grid 64; block 256 = 4 waves; wave = 16 rows; lane = 4*row_local + chunk.
__global__ void __launch_bounds__(256, 1) kA_gram(const float* __restrict__ events,
                                                  float* __restrict__ ws) {
    __shared__ float part[4][136];
    const int tid  = threadIdx.x;
    const int wv   = tid >> 6;
    const int l    = tid & 63;
    const int rl   = l >> 2;
    const int ch   = l & 3;
    const int rowg = blockIdx.x * 64 + wv * 16 + rl;   // [0,4096) = (b,cf)
    const float* xp = events + (size_t)rowg * TT;

    float win[32];
    if (ch < 3) {
#pragma unroll
        for (int k = 0; k < 8; ++k) {
            float4 v = reinterpret_cast<const float4*>(xp + 16 * ch)[k];
            win[4*k] = v.x; win[4*k+1] = v.y; win[4*k+2] = v.z; win[4*k+3] = v.w;
        }
    } else {
#pragma unroll
        for (int k = 0; k < 4; ++k) {
            float4 v = reinterpret_cast<const float4*>(xp + 48)[k];
            win[4*k] = v.x; win[4*k+1] = v.y; win[4*k+2] = v.z; win[4*k+3] = v.w;
        }
#pragma unroll
        for (int k = 16; k < 32; ++k) win[k] = 0.f;
    }

    float csum = 0.f;
#pragma unroll
    for (int i = 0; i < 16; ++i) csum += win[i];
    float tot = csum;
    tot += __shfl_xor(tot, 1, 64);
    tot += __shfl_xor(tot, 2, 64);

    float A[16];
#pragma unroll
    for (int lag = 0; lag < 16; ++lag) {
        float a = 0.f;
#pragma unroll
        for (int i = 0; i < 16; ++i) a += win[i] * win[i + lag];
        a += __shfl_xor(a, 1, 64);
        a += __shfl_xor(a, 2, 64);
        A[lag] = a;
    }

    float hs[7];
    hs[0] = win[0];
#pragma unroll
    for (int k = 1; k < 7; ++k) hs[k] = hs[k-1] + win[k];
    float ts[7];
    ts[6] = win[15];
#pragma unroll
    for (int j = 5; j >= 0; --j) ts[j] = ts[j+1] + win[9 + j];

    float H[28];
    {
        int hi2 = 0;
#pragma unroll
        for (int d1 = 9; d1 < 16; ++d1)
#pragma unroll
            for (int lag = 0; lag <= 15 - d1; ++lag) {
                float s = 0.f;
#pragma unroll
                for (int v = 0; v <= d1 - 9; ++v) s += win[v] * win[v + lag];
                H[hi2++] = s;
            }
    }
    float T[28];
    {
        int ti2 = 0;
#pragma unroll
        for (int d1 = 0; d1 <= 6; ++d1)
#pragma unroll
            for (int d2 = d1; d2 <= 6; ++d2) {
                const int lag = d2 - d1;
                float s = 0.f;
#pragma unroll
                for (int i = d1 + 9; i <= 15 - lag; ++i) s += win[i] * win[i + lag];
                T[ti2++] = s;
            }
    }
    const int src3 = l | 3;
    float Tb[28], tsb[7];
#pragma unroll
    for (int k = 0; k < 28; ++k) Tb[k] = __shfl(T[k], src3, 64);
#pragma unroll
    for (int k = 0; k < 7; ++k) tsb[k] = __shfl(ts[k], src3, 64);

    float S1[16];
#pragma unroll
    for (int d = 0; d < 16; ++d)
        S1[d] = (d <= 6) ? (tot - tsb[d]) : ((d <= 8) ? tot : (tot - hs[d - 9]));

    {
        int hI = 0, tI = 0, p = 0;
#pragma unroll
        for (int d1 = 0; d1 < 16; ++d1)
#pragma unroll
            for (int d2 = d1; d2 < 16; ++d2) {
                const int lag = d2 - d1;
                float g = A[lag] - S1[d1] * S1[d2] * (1.f / 65.f);
                if (d1 >= 9) { g -= H[hI]; ++hI; }
                if (d2 <= 6) { g -= Tb[tI]; ++tI; }
                g += __shfl_xor(g, 4, 64);
                g += __shfl_xor(g, 8, 64);
                g += __shfl_xor(g, 16, 64);
                g += __shfl_xor(g, 32, 64);
                if (l == 0) part[wv][p] = g;
                ++p;
            }
    }
    __syncthreads();
    if (tid < 136)
        ws[PART_OFF + blockIdx.x * 136 + tid] =
            part[0][tid] + part[1][tid] + part[2][tid] + part[3][tid];
}

// ---------------- kernel M: reduce partials, fv, MLP, softmax, wk ----------------
__global__ void __launch_bounds__(256, 1) kM_mlp(const float* __restrict__ tc,
        const float* __restrict__ tk, const float* __restrict__ w1,
        const float* __restrict__ b1, const float* __restrict__ w2,
        const float* __restrict__ b2, float* __restrict__ ws) {
    __shared__ float Gf[BB][KK][KK];
    __shared__ float combL[SS * EE * KK];
    __shared__ float fvL[BB * SS];
    const int tid = threadIdx.x;
    for (int V = tid; V < BB * 136; V += 256) {
        int b = V / 136, p = V % 136;
        int pp = p, d1 = 0;
        while (pp >= KK - d1) { pp -= KK - d1; ++d1; }
        int d2 = d1 + pp;
        float acc = 0.f;
        for (int blk = 0; blk < 32; ++blk)
            acc += ws[PART_OFF + (size_t)(b * 32 + blk) * 136 + p];
        Gf[b][d1][d2] = acc;
        Gf[b][d2][d1] = acc;
    }
    {
        int s = tid >> 6;
        float inv = DT_CONST / tc[s];
        float dk[KK]; float dsum = 0.f;
#pragma unroll
        for (int j = 0; j < KK; ++j) { dk[j] = expf(-(float)j * inv); dsum += dk[j]; }
        float rn = 1.f / dsum;
#pragma unroll
        for (int i = 0; i < 4; ++i) {
            float4 v = reinterpret_cast<const float4*>(tk + tid * KK)[i];
            combL[tid * KK + 4*i + 0] = dk[4*i + 0] * rn * v.x;
            combL[tid * KK + 4*i + 1] = dk[4*i + 1] * rn * v.y;
            combL[tid * KK + 4*i + 2] = dk[4*i + 2] * rn * v.z;
            combL[tid * KK + 4*i + 3] = dk[4*i + 3] * rn * v.w;
        }
    }
    __syncthreads();
    {
        float c[KK];
#pragma unroll
        for (int i = 0; i < 4; ++i) {
            float4 v = reinterpret_cast<const float4*>(combL + tid * KK)[i];
            c[4*i] = v.x; c[4*i+1] = v.y; c[4*i+2] = v.z; c[4*i+3] = v.w;
        }
        float acc0 = 0.f, acc1 = 0.f;
#pragma unroll
        for (int d1 = 0; d1 < KK; ++d1) {
            float cd1 = c[d1];
            float t0 = 0.5f * Gf[0][d1][d1] * cd1;
            float t1 = 0.5f * Gf[1][d1][d1] * cd1;
#pragma unroll
            for (int d2 = d1 + 1; d2 < KK; ++d2) {
                t0 += Gf[0][d1][d2] * c[d2];
                t1 += Gf[1][d1][d2] * c[d2];
            }
            acc0 += 2.f * cd1 * t0;
            acc1 += 2.f * cd1 * t1;
        }
#pragma unroll
        for (int sft = 1; sft < 64; sft <<= 1) {
            acc0 += __shfl_xor(acc0, sft, 64);
            acc1 += __shfl_xor(acc1, sft, 64);
        }
        if ((tid & 63) == 0) {
            const float scale = 1.f / 8388608.f;   // 1/(E*(Tp-1)*Cf)
            fvL[(tid >> 6)]     = acc0 * scale;
            fvL[4 + (tid >> 6)] = acc1 * scale;
        }
    }
    __syncthreads();
    {
        int bt = tid >> 7;
        float fv[SS];
#pragma unroll
        for (int s = 0; s < SS; ++s) fv[s] = fvL[bt * SS + s];
        float h[8];
#pragma unroll
        for (int i = 0; i < 8; ++i) {
            float a = b1[i];
#pragma unroll
            for (int s = 0; s < SS; ++s) a += fv[s] * w1[i * SS + s];
            h[i] = a > 0.f ? a : 0.f;
        }
        float lg[SS]; float mx = -1e30f;
#pragma unroll
        for (int s = 0; s < SS; ++s) {
            float a = b2[s];
#pragma unroll
            for (int i = 0; i < 8; ++i) a += h[i] * w2[s * 8 + i];
            lg[s] = a; mx = fmaxf(mx, a);
        }
        float se = 0.f;
#pragma unroll
        for (int s = 0; s < SS; ++s) { lg[s] = expf(lg[s] - mx); se += lg[s]; }
        float attn[SS];
#pragma unroll
        for (int s = 0; s < SS; ++s) attn[s] = lg[s] / se;
#pragma unroll
        for (int k = 0; k < 8; ++k) {
            int o = tid * 8 + k;
            int e = (o >> 4) & 63, dt2 = o & 15;
            float a = 0.f;
#pragma unroll
            for (int s = 0; s < SS; ++s)
                a += attn[s] * combL[(s * EE + e) * KK + dt2];
            ws[WK_OFF + o] = a;
        }
    }
}

// ---------------- kernel C: conv, streaming window (low VGPR), coalesced writes ----
// grid 4096 chunks of 64 rows; block 256 = 4 waves; wave=seg(16/17 t's), lane=row.
// Streaming: iterate input position U, scatter into static accumulators.
template<int SEG>
__device__ __forceinline__ void conv_seg(const float* __restrict__ xr,
                                         const float* __restrict__ wk,
                                         float* __restrict__ bp) {
    constexpr int XBASE = (SEG == 0) ? 0 : (SEG == 1 ? 8 : (SEG == 2 ? 24 : 40));
    constexpr int NQ    = (SEG == 0 || SEG == 3) ? 6 : 8;
    constexpr int NACC  = (SEG == 3) ? 17 : 16;
    float acc[NACC];
#pragma unroll
    for (int i = 0; i < NACC; ++i) acc[i] = 0.f;
#pragma unroll
    for (int q = 0; q < NQ; ++q) {
        float4 v = reinterpret_cast<const float4*>(xr + XBASE)[q];
#pragma unroll
        for (int j = 0; j < 4; ++j) {
            const int U = XBASE + 4 * q + j - (SEG * 16 - 8);   // compile-time
            const float xv = (j == 0) ? v.x : (j == 1) ? v.y : (j == 2) ? v.z : v.w;
            const int ilo = (U - 15 > 0) ? U - 15 : 0;
            const int ihi = (U < NACC - 1) ? U : NACC - 1;
#pragma unroll
            for (int i = ilo; i <= ihi; ++i)
                acc[i] += wk[U - i] * xv;
        }
    }
#pragma unroll
    for (int i = 0; i < NACC; ++i) bp[i] = acc[i];
}

__global__ void __launch_bounds__(256, 4) kC_conv(const float* __restrict__ events,
                                                  const float* __restrict__ ws,
                                                  float* __restrict__ out) {
    __shared__ float buf[64 * TP];               // 16640 B
    const int tid = threadIdx.x;
    const int seg = tid >> 6;                    // wave-uniform
    const int r   = tid & 63;
    const int c   = blockIdx.x;                  // [0,4096)
    const int be  = c >> 5;
    const int rowg = (c << 6) + r;
    const int b   = be >> 6;
    const float* xr = events + (((size_t)b << 11) + (rowg & (CF - 1))) * TT;

    float wk[KK];
#pragma unroll
    for (int i = 0; i < 4; ++i) {
        float4 v = reinterpret_cast<const float4*>(ws + WK_OFF + be * KK)[i];
        wk[4*i] = v.x; wk[4*i+1] = v.y; wk[4*i+2] = v.z; wk[4*i+3] = v.w;
    }

    float* bp = buf + r * TP + seg * 16;
    if (seg == 0)      conv_seg<0>(xr, wk, bp);
    else if (seg == 1) conv_seg<1>(xr, wk, bp);
    else if (seg == 2) conv_seg<2>(xr, wk, bp);
    else               conv_seg<3>(xr, wk, bp);
    __syncthreads();

    const float4* bs = reinterpret_cast<const float4*>(buf);
    float4* od = reinterpret_cast<float4*>(out + (size_t)c * (64 * TP));
    for (int j = tid; j < 64 * TP / 4; j += 256)
        od[j] = bs[j];
}

extern "C" void kernel_launch(void* const* d_in, const int* in_sizes, int n_in,
                              void* d_out, int out_size, void* d_ws, size_t ws_size,
                              hipStream_t stream) {
    const float* events = (const float*)d_in[0];
    const float* tc     = (const float*)d_in[1];
    const float* tk     = (const float*)d_in[2];
    const float* w1     = (const float*)d_in[3];
    const float* b1     = (const float*)d_in[4];
    const float* w2     = (const float*)d_in[5];
    const float* b2     = (const float*)d_in[6];
    float* out = (float*)d_out;
    float* ws  = (float*)d_ws;

    hipLaunchKernelGGL(kA_gram, dim3(64),   dim3(256), 0, stream, events, ws);
    hipLaunchKernelGGL(kM_mlp,  dim3(1),    dim3(256), 0, stream, tc, tk, w1, b1, w2, b2, ws);
    hipLaunchKernelGGL(kC_conv, dim3(4096), dim3(256), 0, stream, events, ws, out);
}

// Round 6
// 59.293 us; speedup vs baseline: 1.1294x; 1.1294x over previous
//
#include <hip/hip_runtime.h>

#define CF 2048
#define TT 64
#define TP 65
#define KK 16
#define SS 4
#define EE 64
#define BB 2
#define DT_CONST 0.005f

// ws layout (floats)
#define PART_OFF 0        // gram partials [256 blocks][136]
#define WK_OFF   34816    // wk [2][64][16] = 2048

// ---------------- kernel A: windowed Gram, scratch-free, 1 wave/block ----------------
// grid 256; block 64 = 1 wave = 16 rows; lane = 4*row_local + chunk.
__global__ void __launch_bounds__(64) kA_gram(const float* __restrict__ events,
                                              float* __restrict__ ws) {
    __shared__ float part[136];
    const int l    = threadIdx.x;
    const int rl   = l >> 2;
    const int ch   = l & 3;
    const int rowg = blockIdx.x * 16 + rl;             // [0,4096) = (b,cf)
    const float* xp = events + (size_t)rowg * TT;

    float win[32];
    if (ch < 3) {
#pragma unroll
        for (int k = 0; k < 8; ++k) {
            float4 v = reinterpret_cast<const float4*>(xp + 16 * ch)[k];
            win[4*k] = v.x; win[4*k+1] = v.y; win[4*k+2] = v.z; win[4*k+3] = v.w;
        }
    } else {
#pragma unroll
        for (int k = 0; k < 4; ++k) {
            float4 v = reinterpret_cast<const float4*>(xp + 48)[k];
            win[4*k] = v.x; win[4*k+1] = v.y; win[4*k+2] = v.z; win[4*k+3] = v.w;
        }
#pragma unroll
        for (int k = 16; k < 32; ++k) win[k] = 0.f;
    }

    float csum = 0.f;
#pragma unroll
    for (int i = 0; i < 16; ++i) csum += win[i];
    float tot = csum;
    tot += __shfl_xor(tot, 1, 64);
    tot += __shfl_xor(tot, 2, 64);

    float A[16];
#pragma unroll
    for (int lag = 0; lag < 16; ++lag) {
        float a = 0.f;
#pragma unroll
        for (int i = 0; i < 16; ++i) a += win[i] * win[i + lag];
        a += __shfl_xor(a, 1, 64);
        a += __shfl_xor(a, 2, 64);
        A[lag] = a;
    }

    float hs[7];
    hs[0] = win[0];
#pragma unroll
    for (int k = 1; k < 7; ++k) hs[k] = hs[k-1] + win[k];
    float ts[7];
    ts[6] = win[15];
#pragma unroll
    for (int j = 5; j >= 0; --j) ts[j] = ts[j+1] + win[9 + j];

    float H[28];
    {
        int hi2 = 0;
#pragma unroll
        for (int d1 = 9; d1 < 16; ++d1)
#pragma unroll
            for (int lag = 0; lag <= 15 - d1; ++lag) {
                float s = 0.f;
#pragma unroll
                for (int v = 0; v <= d1 - 9; ++v) s += win[v] * win[v + lag];
                H[hi2++] = s;
            }
    }
    float T[28];
    {
        int ti2 = 0;
#pragma unroll
        for (int d1 = 0; d1 <= 6; ++d1)
#pragma unroll
            for (int d2 = d1; d2 <= 6; ++d2) {
                const int lag = d2 - d1;
                float s = 0.f;
#pragma unroll
                for (int i = d1 + 9; i <= 15 - lag; ++i) s += win[i] * win[i + lag];
                T[ti2++] = s;
            }
    }
    const int src3 = l | 3;
    float Tb[28], tsb[7];
#pragma unroll
    for (int k = 0; k < 28; ++k) Tb[k] = __shfl(T[k], src3, 64);
#pragma unroll
    for (int k = 0; k < 7; ++k) tsb[k] = __shfl(ts[k], src3, 64);

    float S1[16];
#pragma unroll
    for (int d = 0; d < 16; ++d)
        S1[d] = (d <= 6) ? (tot - tsb[d]) : ((d <= 8) ? tot : (tot - hs[d - 9]));

    {
        int hI = 0, tI = 0, p = 0;
#pragma unroll
        for (int d1 = 0; d1 < 16; ++d1)
#pragma unroll
            for (int d2 = d1; d2 < 16; ++d2) {
                const int lag = d2 - d1;
                float g = A[lag] - S1[d1] * S1[d2] * (1.f / 65.f);
                if (d1 >= 9) { g -= H[hI]; ++hI; }
                if (d2 <= 6) { g -= Tb[tI]; ++tI; }
                g += __shfl_xor(g, 4, 64);
                g += __shfl_xor(g, 8, 64);
                g += __shfl_xor(g, 16, 64);
                g += __shfl_xor(g, 32, 64);
                if (l == 0) part[p] = g;
                ++p;
            }
    }
    __syncthreads();
#pragma unroll
    for (int base = 0; base < 136; base += 64) {
        int idx = base + l;
        if (idx < 136)
            ws[PART_OFF + blockIdx.x * 136 + idx] = part[idx];
    }
}

// ---------------- kernel M: reduce 256 partial sets, fv, MLP, softmax, wk ----------------
__global__ void __launch_bounds__(256, 1) kM_mlp(const float* __restrict__ tc,
        const float* __restrict__ tk, const float* __restrict__ w1,
        const float* __restrict__ b1, const float* __restrict__ w2,
        const float* __restrict__ b2, float* __restrict__ ws) {
    __shared__ float Gf[BB][KK][KK];
    __shared__ float combL[SS * EE * KK];
    __shared__ float fvL[BB * SS];
    const int tid = threadIdx.x;
    for (int V = tid; V < BB * 136; V += 256) {
        int b = V / 136, p = V % 136;
        int pp = p, d1 = 0;
        while (pp >= KK - d1) { pp -= KK - d1; ++d1; }
        int d2 = d1 + pp;
        float acc = 0.f;
        for (int blk = 0; blk < 128; ++blk)
            acc += ws[PART_OFF + (size_t)(b * 128 + blk) * 136 + p];
        Gf[b][d1][d2] = acc;
        Gf[b][d2][d1] = acc;
    }
    {
        int s = tid >> 6;
        float inv = DT_CONST / tc[s];
        float dk[KK]; float dsum = 0.f;
#pragma unroll
        for (int j = 0; j < KK; ++j) { dk[j] = expf(-(float)j * inv); dsum += dk[j]; }
        float rn = 1.f / dsum;
#pragma unroll
        for (int i = 0; i < 4; ++i) {
            float4 v = reinterpret_cast<const float4*>(tk + tid * KK)[i];
            combL[tid * KK + 4*i + 0] = dk[4*i + 0] * rn * v.x;
            combL[tid * KK + 4*i + 1] = dk[4*i + 1] * rn * v.y;
            combL[tid * KK + 4*i + 2] = dk[4*i + 2] * rn * v.z;
            combL[tid * KK + 4*i + 3] = dk[4*i + 3] * rn * v.w;
        }
    }
    __syncthreads();
    {
        float c[KK];
#pragma unroll
        for (int i = 0; i < 4; ++i) {
            float4 v = reinterpret_cast<const float4*>(combL + tid * KK)[i];
            c[4*i] = v.x; c[4*i+1] = v.y; c[4*i+2] = v.z; c[4*i+3] = v.w;
        }
        float acc0 = 0.f, acc1 = 0.f;
#pragma unroll
        for (int d1 = 0; d1 < KK; ++d1) {
            float cd1 = c[d1];
            float t0 = 0.5f * Gf[0][d1][d1] * cd1;
            float t1 = 0.5f * Gf[1][d1][d1] * cd1;
#pragma unroll
            for (int d2 = d1 + 1; d2 < KK; ++d2) {
                t0 += Gf[0][d1][d2] * c[d2];
                t1 += Gf[1][d1][d2] * c[d2];
            }
            acc0 += 2.f * cd1 * t0;
            acc1 += 2.f * cd1 * t1;
        }
#pragma unroll
        for (int sft = 1; sft < 64; sft <<= 1) {
            acc0 += __shfl_xor(acc0, sft, 64);
            acc1 += __shfl_xor(acc1, sft, 64);
        }
        if ((tid & 63) == 0) {
            const float scale = 1.f / 8388608.f;   // 1/(E*(Tp-1)*Cf)
            fvL[(tid >> 6)]     = acc0 * scale;
            fvL[4 + (tid >> 6)] = acc1 * scale;
        }
    }
    __syncthreads();
    {
        int bt = tid >> 7;
        float fv[SS];
#pragma unroll
        for (int s = 0; s < SS; ++s) fv[s] = fvL[bt * SS + s];
        float h[8];
#pragma unroll
        for (int i = 0; i < 8; ++i) {
            float a = b1[i];
#pragma unroll
            for (int s = 0; s < SS; ++s) a += fv[s] * w1[i * SS + s];
            h[i] = a > 0.f ? a : 0.f;
        }
        float lg[SS]; float mx = -1e30f;
#pragma unroll
        for (int s = 0; s < SS; ++s) {
            float a = b2[s];
#pragma unroll
            for (int i = 0; i < 8; ++i) a += h[i] * w2[s * 8 + i];
            lg[s] = a; mx = fmaxf(mx, a);
        }
        float se = 0.f;
#pragma unroll
        for (int s = 0; s < SS; ++s) { lg[s] = expf(lg[s] - mx); se += lg[s]; }
        float attn[SS];
#pragma unroll
        for (int s = 0; s < SS; ++s) attn[s] = lg[s] / se;
#pragma unroll
        for (int k = 0; k < 8; ++k) {
            int o = tid * 8 + k;
            int e = (o >> 4) & 63, dt2 = o & 15;
            float a = 0.f;
#pragma unroll
            for (int s = 0; s < SS; ++s)
                a += attn[s] * combL[(s * EE + e) * KK + dt2];
            ws[WK_OFF + o] = a;
        }
    }
}

// ---------------- kernel C: conv, seg-chunked (round-4 version), coalesced writes ----
// grid 4096 chunks of 64 rows; block 256 = 4 waves; wave=seg(16/17 t's), lane=row.
__global__ void __launch_bounds__(256, 4) kC_conv(const float* __restrict__ events,
                                                  const float* __restrict__ ws,
                                                  float* __restrict__ out) {
    __shared__ float buf[64 * TP];               // 16640 B
    const int tid = threadIdx.x;
    const int seg = tid >> 6;                    // wave-uniform
    const int r   = tid & 63;
    const int c   = blockIdx.x;                  // [0,4096)
    const int be  = c >> 5;
    const int rowg = (c << 6) + r;
    const int b   = be >> 6;
    const float* xr = events + (((size_t)b << 11) + (rowg & (CF - 1))) * TT;

    float wk[KK];
#pragma unroll
    for (int i = 0; i < 4; ++i) {
        float4 v = reinterpret_cast<const float4*>(ws + WK_OFF + be * KK)[i];
        wk[4*i] = v.x; wk[4*i+1] = v.y; wk[4*i+2] = v.z; wk[4*i+3] = v.w;
    }

    float win[32];
    if (seg == 0) {                              // t 0..15, u -8..22
#pragma unroll
        for (int k = 0; k < 8; ++k) win[k] = 0.f;
#pragma unroll
        for (int k = 0; k < 6; ++k) {
            float4 v = reinterpret_cast<const float4*>(xr)[k];
            win[8+4*k] = v.x; win[9+4*k] = v.y; win[10+4*k] = v.z; win[11+4*k] = v.w;
        }
    } else if (seg == 3) {                       // t 48..64, u 40..71
#pragma unroll
        for (int k = 0; k < 6; ++k) {
            float4 v = reinterpret_cast<const float4*>(xr + 40)[k];
            win[4*k] = v.x; win[4*k+1] = v.y; win[4*k+2] = v.z; win[4*k+3] = v.w;
        }
#pragma unroll
        for (int k = 24; k < 32; ++k) win[k] = 0.f;
    } else {                                     // seg1: u 8..39, seg2: u 24..55
        const float* bp2 = xr + (seg == 1 ? 8 : 24);
#pragma unroll
        for (int k = 0; k < 8; ++k) {
            float4 v = reinterpret_cast<const float4*>(bp2)[k];
            win[4*k] = v.x; win[4*k+1] = v.y; win[4*k+2] = v.z; win[4*k+3] = v.w;
        }
    }

    float acc[16];
#pragma unroll
    for (int i = 0; i < 16; ++i) acc[i] = 0.f;
#pragma unroll
    for (int dt = 0; dt < 16; ++dt) {
        float w = wk[dt];
#pragma unroll
        for (int i = 0; i < 16; ++i) acc[i] += w * win[i + dt];
    }
    float acc16 = 0.f;
    if (seg == 3) {
#pragma unroll
        for (int dt = 0; dt < 8; ++dt) acc16 += wk[dt] * win[16 + dt];
    }

    float* bp = buf + r * TP + seg * 16;
#pragma unroll
    for (int i = 0; i < 16; ++i) bp[i] = acc[i];
    if (seg == 3) bp[16] = acc16;
    __syncthreads();

    const float4* bs = reinterpret_cast<const float4*>(buf);
    float4* od = reinterpret_cast<float4*>(out + (size_t)c * (64 * TP));
    for (int j = tid; j < 64 * TP / 4; j += 256)
        od[j] = bs[j];
}

extern "C" void kernel_launch(void* const* d_in, const int* in_sizes, int n_in,
                              void* d_out, int out_size, void* d_ws, size_t ws_size,
                              hipStream_t stream) {
    const float* events = (const float*)d_in[0];
    const float* tc     = (const float*)d_in[1];
    const float* tk     = (const float*)d_in[2];
    const float* w1     = (const float*)d_in[3];
    const float* b1     = (const float*)d_in[4];
    const float* w2     = (const float*)d_in[5];
    const float* b2     = (const float*)d_in[6];
    float* out = (float*)d_out;
    float* ws  = (float*)d_ws;

    hipLaunchKernelGGL(kA_gram, dim3(256),  dim3(64),  0, stream, events, ws);
    hipLaunchKernelGGL(kM_mlp,  dim3(1),    dim3(256), 0, stream, tc, tk, w1, b1, w2, b2, ws);
    hipLaunchKernelGGL(kC_conv, dim3(4096), dim3(256), 0, stream, events, ws, out);
}

// Round 7
// 58.167 us; speedup vs baseline: 1.1512x; 1.0194x over previous
//
#include <hip/hip_runtime.h>

#define CF 2048
#define TT 64
#define TP 65
#define KK 16
#define SS 4
#define EE 64
#define BB 2
#define DT_CONST 0.005f

// ws layout (floats)
#define PART_OFF 0        // gram partials [64 blocks][136]
#define WK_OFF   8704     // wk [2][64][16] = 2048

// ---------------- kernel A: windowed Gram, scratch-free (R4 version) ----------------
// grid 64; block 256 = 4 waves; wave = 16 rows; lane = 4*row_local + chunk.
__global__ void __launch_bounds__(256, 1) kA_gram(const float* __restrict__ events,
                                                  float* __restrict__ ws) {
    __shared__ float part[4][136];
    const int tid  = threadIdx.x;
    const int wv   = tid >> 6;
    const int l    = tid & 63;
    const int rl   = l >> 2;
    const int ch   = l & 3;
    const int rowg = blockIdx.x * 64 + wv * 16 + rl;   // [0,4096) = (b,cf)
    const float* xp = events + (size_t)rowg * TT;

    float win[32];
    if (ch < 3) {
#pragma unroll
        for (int k = 0; k < 8; ++k) {
            float4 v = reinterpret_cast<const float4*>(xp + 16 * ch)[k];
            win[4*k] = v.x; win[4*k+1] = v.y; win[4*k+2] = v.z; win[4*k+3] = v.w;
        }
    } else {
#pragma unroll
        for (int k = 0; k < 4; ++k) {
            float4 v = reinterpret_cast<const float4*>(xp + 48)[k];
            win[4*k] = v.x; win[4*k+1] = v.y; win[4*k+2] = v.z; win[4*k+3] = v.w;
        }
#pragma unroll
        for (int k = 16; k < 32; ++k) win[k] = 0.f;
    }

    float csum = 0.f;
#pragma unroll
    for (int i = 0; i < 16; ++i) csum += win[i];
    float tot = csum;
    tot += __shfl_xor(tot, 1, 64);
    tot += __shfl_xor(tot, 2, 64);

    float A[16];
#pragma unroll
    for (int lag = 0; lag < 16; ++lag) {
        float a = 0.f;
#pragma unroll
        for (int i = 0; i < 16; ++i) a += win[i] * win[i + lag];
        a += __shfl_xor(a, 1, 64);
        a += __shfl_xor(a, 2, 64);
        A[lag] = a;
    }

    float hs[7];
    hs[0] = win[0];
#pragma unroll
    for (int k = 1; k < 7; ++k) hs[k] = hs[k-1] + win[k];
    float ts[7];
    ts[6] = win[15];
#pragma unroll
    for (int j = 5; j >= 0; --j) ts[j] = ts[j+1] + win[9 + j];

    float H[28];
    {
        int hi2 = 0;
#pragma unroll
        for (int d1 = 9; d1 < 16; ++d1)
#pragma unroll
            for (int lag = 0; lag <= 15 - d1; ++lag) {
                float s = 0.f;
#pragma unroll
                for (int v = 0; v <= d1 - 9; ++v) s += win[v] * win[v + lag];
                H[hi2++] = s;
            }
    }
    float T[28];
    {
        int ti2 = 0;
#pragma unroll
        for (int d1 = 0; d1 <= 6; ++d1)
#pragma unroll
            for (int d2 = d1; d2 <= 6; ++d2) {
                const int lag = d2 - d1;
                float s = 0.f;
#pragma unroll
                for (int i = d1 + 9; i <= 15 - lag; ++i) s += win[i] * win[i + lag];
                T[ti2++] = s;
            }
    }
    const int src3 = l | 3;
    float Tb[28], tsb[7];
#pragma unroll
    for (int k = 0; k < 28; ++k) Tb[k] = __shfl(T[k], src3, 64);
#pragma unroll
    for (int k = 0; k < 7; ++k) tsb[k] = __shfl(ts[k], src3, 64);

    float S1[16];
#pragma unroll
    for (int d = 0; d < 16; ++d)
        S1[d] = (d <= 6) ? (tot - tsb[d]) : ((d <= 8) ? tot : (tot - hs[d - 9]));

    {
        int hI = 0, tI = 0, p = 0;
#pragma unroll
        for (int d1 = 0; d1 < 16; ++d1)
#pragma unroll
            for (int d2 = d1; d2 < 16; ++d2) {
                const int lag = d2 - d1;
                float g = A[lag] - S1[d1] * S1[d2] * (1.f / 65.f);
                if (d1 >= 9) { g -= H[hI]; ++hI; }
                if (d2 <= 6) { g -= Tb[tI]; ++tI; }
                g += __shfl_xor(g, 4, 64);
                g += __shfl_xor(g, 8, 64);
                g += __shfl_xor(g, 16, 64);
                g += __shfl_xor(g, 32, 64);
                if (l == 0) part[wv][p] = g;
                ++p;
            }
    }
    __syncthreads();
    if (tid < 136)
        ws[PART_OFF + blockIdx.x * 136 + tid] =
            part[0][tid] + part[1][tid] + part[2][tid] + part[3][tid];
}

// ---------------- kernel M: reduce partials, fv, MLP, softmax, wk (R4 version) ----------------
__global__ void __launch_bounds__(256, 1) kM_mlp(const float* __restrict__ tc,
        const float* __restrict__ tk, const float* __restrict__ w1,
        const float* __restrict__ b1, const float* __restrict__ w2,
        const float* __restrict__ b2, float* __restrict__ ws) {
    __shared__ float Gf[BB][KK][KK];
    __shared__ float combL[SS * EE * KK];
    __shared__ float fvL[BB * SS];
    const int tid = threadIdx.x;
    for (int V = tid; V < BB * 136; V += 256) {
        int b = V / 136, p = V % 136;
        int pp = p, d1 = 0;
        while (pp >= KK - d1) { pp -= KK - d1; ++d1; }
        int d2 = d1 + pp;
        float acc = 0.f;
        for (int blk = 0; blk < 32; ++blk)
            acc += ws[PART_OFF + (size_t)(b * 32 + blk) * 136 + p];
        Gf[b][d1][d2] = acc;
        Gf[b][d2][d1] = acc;
    }
    {
        int s = tid >> 6;
        float inv = DT_CONST / tc[s];
        float dk[KK]; float dsum = 0.f;
#pragma unroll
        for (int j = 0; j < KK; ++j) { dk[j] = expf(-(float)j * inv); dsum += dk[j]; }
        float rn = 1.f / dsum;
#pragma unroll
        for (int i = 0; i < 4; ++i) {
            float4 v = reinterpret_cast<const float4*>(tk + tid * KK)[i];
            combL[tid * KK + 4*i + 0] = dk[4*i + 0] * rn * v.x;
            combL[tid * KK + 4*i + 1] = dk[4*i + 1] * rn * v.y;
            combL[tid * KK + 4*i + 2] = dk[4*i + 2] * rn * v.z;
            combL[tid * KK + 4*i + 3] = dk[4*i + 3] * rn * v.w;
        }
    }
    __syncthreads();
    {
        float c[KK];
#pragma unroll
        for (int i = 0; i < 4; ++i) {
            float4 v = reinterpret_cast<const float4*>(combL + tid * KK)[i];
            c[4*i] = v.x; c[4*i+1] = v.y; c[4*i+2] = v.z; c[4*i+3] = v.w;
        }
        float acc0 = 0.f, acc1 = 0.f;
#pragma unroll
        for (int d1 = 0; d1 < KK; ++d1) {
            float cd1 = c[d1];
            float t0 = 0.5f * Gf[0][d1][d1] * cd1;
            float t1 = 0.5f * Gf[1][d1][d1] * cd1;
#pragma unroll
            for (int d2 = d1 + 1; d2 < KK; ++d2) {
                t0 += Gf[0][d1][d2] * c[d2];
                t1 += Gf[1][d1][d2] * c[d2];
            }
            acc0 += 2.f * cd1 * t0;
            acc1 += 2.f * cd1 * t1;
        }
#pragma unroll
        for (int sft = 1; sft < 64; sft <<= 1) {
            acc0 += __shfl_xor(acc0, sft, 64);
            acc1 += __shfl_xor(acc1, sft, 64);
        }
        if ((tid & 63) == 0) {
            const float scale = 1.f / 8388608.f;   // 1/(E*(Tp-1)*Cf)
            fvL[(tid >> 6)]     = acc0 * scale;
            fvL[4 + (tid >> 6)] = acc1 * scale;
        }
    }
    __syncthreads();
    {
        int bt = tid >> 7;
        float fv[SS];
#pragma unroll
        for (int s = 0; s < SS; ++s) fv[s] = fvL[bt * SS + s];
        float h[8];
#pragma unroll
        for (int i = 0; i < 8; ++i) {
            float a = b1[i];
#pragma unroll
            for (int s = 0; s < SS; ++s) a += fv[s] * w1[i * SS + s];
            h[i] = a > 0.f ? a : 0.f;
        }
        float lg[SS]; float mx = -1e30f;
#pragma unroll
        for (int s = 0; s < SS; ++s) {
            float a = b2[s];
#pragma unroll
            for (int i = 0; i < 8; ++i) a += h[i] * w2[s * 8 + i];
            lg[s] = a; mx = fmaxf(mx, a);
        }
        float se = 0.f;
#pragma unroll
        for (int s = 0; s < SS; ++s) { lg[s] = expf(lg[s] - mx); se += lg[s]; }
        float attn[SS];
#pragma unroll
        for (int s = 0; s < SS; ++s) attn[s] = lg[s] / se;
#pragma unroll
        for (int k = 0; k < 8; ++k) {
            int o = tid * 8 + k;
            int e = (o >> 4) & 63, dt2 = o & 15;
            float a = 0.f;
#pragma unroll
            for (int s = 0; s < SS; ++s)
                a += attn[s] * combL[(s * EE + e) * KK + dt2];
            ws[WK_OFF + o] = a;
        }
    }
}

// ---------------- kernel C2: conv, R2 geometry (256 rows/block) + spill-free segs ----
// grid 1024; block 256 = 4 waves; wave = seg (uniform), lane = row%64;
// each thread does 4 (row,seg) tasks, win[32]/acc reused (unroll 1 on task loop).
__global__ void __launch_bounds__(256, 2) kC2_conv(const float* __restrict__ events,
                                                   const float* __restrict__ ws,
                                                   float* __restrict__ out) {
    __shared__ float buf[256 * TP];              // 66560 B
    const int tid = threadIdx.x;
    const int seg = tid >> 6;                    // wave-uniform
    const int r0  = tid & 63;
    const int c   = blockIdx.x;                  // [0,1024)
    const int be  = c >> 3;                      // uniform per block
    const int b   = be >> 6;

    float wk[KK];
#pragma unroll
    for (int i = 0; i < 4; ++i) {
        float4 v = reinterpret_cast<const float4*>(ws + WK_OFF + be * KK)[i];
        wk[4*i] = v.x; wk[4*i+1] = v.y; wk[4*i+2] = v.z; wk[4*i+3] = v.w;
    }

#pragma unroll 1
    for (int it = 0; it < 4; ++it) {
        const int row = r0 + (it << 6);          // [0,256)
        const int cf  = ((c << 8) + row) & (CF - 1);
        const float* xr = events + (((size_t)b << 11) + cf) * TT;

        float win[32];
        if (seg == 0) {                          // t 0..15, u -8..22
#pragma unroll
            for (int k = 0; k < 8; ++k) win[k] = 0.f;
#pragma unroll
            for (int k = 0; k < 6; ++k) {
                float4 v = reinterpret_cast<const float4*>(xr)[k];
                win[8+4*k] = v.x; win[9+4*k] = v.y; win[10+4*k] = v.z; win[11+4*k] = v.w;
            }
        } else if (seg == 3) {                   // t 48..64, u 40..71
#pragma unroll
            for (int k = 0; k < 6; ++k) {
                float4 v = reinterpret_cast<const float4*>(xr + 40)[k];
                win[4*k] = v.x; win[4*k+1] = v.y; win[4*k+2] = v.z; win[4*k+3] = v.w;
            }
#pragma unroll
            for (int k = 24; k < 32; ++k) win[k] = 0.f;
        } else {                                 // seg1: u 8..39, seg2: u 24..55
            const float* bp2 = xr + (seg == 1 ? 8 : 24);
#pragma unroll
            for (int k = 0; k < 8; ++k) {
                float4 v = reinterpret_cast<const float4*>(bp2)[k];
                win[4*k] = v.x; win[4*k+1] = v.y; win[4*k+2] = v.z; win[4*k+3] = v.w;
            }
        }

        float acc[16];
#pragma unroll
        for (int i = 0; i < 16; ++i) acc[i] = 0.f;
#pragma unroll
        for (int dt = 0; dt < 16; ++dt) {
            float w = wk[dt];
#pragma unroll
            for (int i = 0; i < 16; ++i) acc[i] += w * win[i + dt];
        }
        float acc16 = 0.f;
        if (seg == 3) {
#pragma unroll
            for (int dt = 0; dt < 8; ++dt) acc16 += wk[dt] * win[16 + dt];
        }

        float* bp = buf + row * TP + seg * 16;
#pragma unroll
        for (int i = 0; i < 16; ++i) bp[i] = acc[i];
        if (seg == 3) bp[16] = acc16;
    }
    __syncthreads();

    const float4* bs = reinterpret_cast<const float4*>(buf);
    float4* od = reinterpret_cast<float4*>(out + (size_t)c * (256 * TP));
    for (int j = tid; j < 256 * TP / 4; j += 256)
        od[j] = bs[j];
}

extern "C" void kernel_launch(void* const* d_in, const int* in_sizes, int n_in,
                              void* d_out, int out_size, void* d_ws, size_t ws_size,
                              hipStream_t stream) {
    const float* events = (const float*)d_in[0];
    const float* tc     = (const float*)d_in[1];
    const float* tk     = (const float*)d_in[2];
    const float* w1     = (const float*)d_in[3];
    const float* b1     = (const float*)d_in[4];
    const float* w2     = (const float*)d_in[5];
    const float* b2     = (const float*)d_in[6];
    float* out = (float*)d_out;
    float* ws  = (float*)d_ws;

    hipLaunchKernelGGL(kA_gram,  dim3(64),   dim3(256), 0, stream, events, ws);
    hipLaunchKernelGGL(kM_mlp,   dim3(1),    dim3(256), 0, stream, tc, tk, w1, b1, w2, b2, ws);
    hipLaunchKernelGGL(kC2_conv, dim3(1024), dim3(256), 0, stream, events, ws, out);
}

// Round 8
// 55.141 us; speedup vs baseline: 1.2144x; 1.0549x over previous
//
#include <hip/hip_runtime.h>

#define CF 2048
#define TT 64
#define TP 65
#define KK 16
#define SS 4
#define EE 64
#define BB 2
#define DT_CONST 0.005f

// ws: gram partials [64 blocks][136]

// ---------------- kernel A: windowed Gram, scratch-free (R4 verbatim) ----------------
__global__ void __launch_bounds__(256, 1) kA_gram(const float* __restrict__ events,
                                                  float* __restrict__ ws) {
    __shared__ float part[4][136];
    const int tid  = threadIdx.x;
    const int wv   = tid >> 6;
    const int l    = tid & 63;
    const int rl   = l >> 2;
    const int ch   = l & 3;
    const int rowg = blockIdx.x * 64 + wv * 16 + rl;   // [0,4096) = (b,cf)
    const float* xp = events + (size_t)rowg * TT;

    float win[32];
    if (ch < 3) {
#pragma unroll
        for (int k = 0; k < 8; ++k) {
            float4 v = reinterpret_cast<const float4*>(xp + 16 * ch)[k];
            win[4*k] = v.x; win[4*k+1] = v.y; win[4*k+2] = v.z; win[4*k+3] = v.w;
        }
    } else {
#pragma unroll
        for (int k = 0; k < 4; ++k) {
            float4 v = reinterpret_cast<const float4*>(xp + 48)[k];
            win[4*k] = v.x; win[4*k+1] = v.y; win[4*k+2] = v.z; win[4*k+3] = v.w;
        }
#pragma unroll
        for (int k = 16; k < 32; ++k) win[k] = 0.f;
    }

    float csum = 0.f;
#pragma unroll
    for (int i = 0; i < 16; ++i) csum += win[i];
    float tot = csum;
    tot += __shfl_xor(tot, 1, 64);
    tot += __shfl_xor(tot, 2, 64);

    float A[16];
#pragma unroll
    for (int lag = 0; lag < 16; ++lag) {
        float a = 0.f;
#pragma unroll
        for (int i = 0; i < 16; ++i) a += win[i] * win[i + lag];
        a += __shfl_xor(a, 1, 64);
        a += __shfl_xor(a, 2, 64);
        A[lag] = a;
    }

    float hs[7];
    hs[0] = win[0];
#pragma unroll
    for (int k = 1; k < 7; ++k) hs[k] = hs[k-1] + win[k];
    float ts[7];
    ts[6] = win[15];
#pragma unroll
    for (int j = 5; j >= 0; --j) ts[j] = ts[j+1] + win[9 + j];

    float H[28];
    {
        int hi2 = 0;
#pragma unroll
        for (int d1 = 9; d1 < 16; ++d1)
#pragma unroll
            for (int lag = 0; lag <= 15 - d1; ++lag) {
                float s = 0.f;
#pragma unroll
                for (int v = 0; v <= d1 - 9; ++v) s += win[v] * win[v + lag];
                H[hi2++] = s;
            }
    }
    float T[28];
    {
        int ti2 = 0;
#pragma unroll
        for (int d1 = 0; d1 <= 6; ++d1)
#pragma unroll
            for (int d2 = d1; d2 <= 6; ++d2) {
                const int lag = d2 - d1;
                float s = 0.f;
#pragma unroll
                for (int i = d1 + 9; i <= 15 - lag; ++i) s += win[i] * win[i + lag];
                T[ti2++] = s;
            }
    }
    const int src3 = l | 3;
    float Tb[28], tsb[7];
#pragma unroll
    for (int k = 0; k < 28; ++k) Tb[k] = __shfl(T[k], src3, 64);
#pragma unroll
    for (int k = 0; k < 7; ++k) tsb[k] = __shfl(ts[k], src3, 64);

    float S1[16];
#pragma unroll
    for (int d = 0; d < 16; ++d)
        S1[d] = (d <= 6) ? (tot - tsb[d]) : ((d <= 8) ? tot : (tot - hs[d - 9]));

    {
        int hI = 0, tI = 0, p = 0;
#pragma unroll
        for (int d1 = 0; d1 < 16; ++d1)
#pragma unroll
            for (int d2 = d1; d2 < 16; ++d2) {
                const int lag = d2 - d1;
                float g = A[lag] - S1[d1] * S1[d2] * (1.f / 65.f);
                if (d1 >= 9) { g -= H[hI]; ++hI; }
                if (d2 <= 6) { g -= Tb[tI]; ++tI; }
                g += __shfl_xor(g, 4, 64);
                g += __shfl_xor(g, 8, 64);
                g += __shfl_xor(g, 16, 64);
                g += __shfl_xor(g, 32, 64);
                if (l == 0) part[wv][p] = g;
                ++p;
            }
    }
    __syncthreads();
    if (tid < 136)
        ws[blockIdx.x * 136 + tid] =
            part[0][tid] + part[1][tid] + part[2][tid] + part[3][tid];
}

// ---------------- kernel B2: redundant prologue (kM) + spill-free seg conv ----------
// grid 1024 × 256 thr. Prologue: reduce [64][136] partials -> Gf, comb, fv, MLP, wk
// (all in LDS). Conv: 4 iterations of 64-row chunks, LDS-staged coalesced writes.
__global__ void __launch_bounds__(256, 4) kB2_main(
        const float* __restrict__ events, const float* __restrict__ tc,
        const float* __restrict__ tk, const float* __restrict__ w1,
        const float* __restrict__ b1, const float* __restrict__ w2,
        const float* __restrict__ b2, const float* __restrict__ ws,
        float* __restrict__ out) {
    __shared__ float buf[4672];           // prologue: Gf[512]|combL[4096]|fvL[8]; conv: 64*65=4160
    __shared__ float wkL[BB * EE * KK];   // 2048
    float* Gf    = buf;                   // [2][16][16]
    float* combL = buf + 512;             // [4][64][16]
    float* fvL   = buf + 4608;            // [2][4]
    const int tid = threadIdx.x;

    // --- Gram partial reduce -> full symmetric G per b ---
    for (int V = tid; V < BB * 136; V += 256) {
        int b = V / 136, p = V % 136;
        int pp = p, d1 = 0;
        while (pp >= KK - d1) { pp -= KK - d1; ++d1; }
        int d2 = d1 + pp;
        float acc = 0.f;
#pragma unroll
        for (int blk = 0; blk < 32; ++blk)
            acc += ws[(size_t)(b * 32 + blk) * 136 + p];
        Gf[(b * KK + d1) * KK + d2] = acc;
        Gf[(b * KK + d2) * KK + d1] = acc;
    }
    // --- combined kernels: thread = (s,e) ---
    {
        int s = tid >> 6;
        float inv = DT_CONST / tc[s];
        float dk[KK]; float dsum = 0.f;
#pragma unroll
        for (int j = 0; j < KK; ++j) { dk[j] = expf(-(float)j * inv); dsum += dk[j]; }
        float rn = 1.f / dsum;
#pragma unroll
        for (int i = 0; i < 4; ++i) {
            float4 v = reinterpret_cast<const float4*>(tk + tid * KK)[i];
            combL[tid * KK + 4*i + 0] = dk[4*i + 0] * rn * v.x;
            combL[tid * KK + 4*i + 1] = dk[4*i + 1] * rn * v.y;
            combL[tid * KK + 4*i + 2] = dk[4*i + 2] * rn * v.z;
            combL[tid * KK + 4*i + 3] = dk[4*i + 3] * rn * v.w;
        }
    }
    __syncthreads();
    // --- quadratic forms + e-reduction -> fv ---
    {
        float c[KK];
#pragma unroll
        for (int i = 0; i < 4; ++i) {
            float4 v = reinterpret_cast<const float4*>(combL + tid * KK)[i];
            c[4*i] = v.x; c[4*i+1] = v.y; c[4*i+2] = v.z; c[4*i+3] = v.w;
        }
        float acc0 = 0.f, acc1 = 0.f;
#pragma unroll
        for (int d1 = 0; d1 < KK; ++d1) {
            float cd1 = c[d1];
            float t0 = 0.5f * Gf[d1 * KK + d1] * cd1;
            float t1 = 0.5f * Gf[256 + d1 * KK + d1] * cd1;
#pragma unroll
            for (int d2 = d1 + 1; d2 < KK; ++d2) {
                t0 += Gf[d1 * KK + d2] * c[d2];
                t1 += Gf[256 + d1 * KK + d2] * c[d2];
            }
            acc0 += 2.f * cd1 * t0;
            acc1 += 2.f * cd1 * t1;
        }
#pragma unroll
        for (int sft = 1; sft < 64; sft <<= 1) {
            acc0 += __shfl_xor(acc0, sft, 64);
            acc1 += __shfl_xor(acc1, sft, 64);
        }
        if ((tid & 63) == 0) {
            const float scale = 1.f / 8388608.f;   // 1/(E*(Tp-1)*Cf)
            fvL[(tid >> 6)]     = acc0 * scale;
            fvL[4 + (tid >> 6)] = acc1 * scale;
        }
    }
    __syncthreads();
    // --- MLP + softmax + wk (into LDS) ---
    {
        int bt = tid >> 7;
        float fv[SS];
#pragma unroll
        for (int s = 0; s < SS; ++s) fv[s] = fvL[bt * SS + s];
        float h[8];
#pragma unroll
        for (int i = 0; i < 8; ++i) {
            float a = b1[i];
#pragma unroll
            for (int s = 0; s < SS; ++s) a += fv[s] * w1[i * SS + s];
            h[i] = a > 0.f ? a : 0.f;
        }
        float lg[SS]; float mx = -1e30f;
#pragma unroll
        for (int s = 0; s < SS; ++s) {
            float a = b2[s];
#pragma unroll
            for (int i = 0; i < 8; ++i) a += h[i] * w2[s * 8 + i];
            lg[s] = a; mx = fmaxf(mx, a);
        }
        float se = 0.f;
#pragma unroll
        for (int s = 0; s < SS; ++s) { lg[s] = expf(lg[s] - mx); se += lg[s]; }
        float attn[SS];
#pragma unroll
        for (int s = 0; s < SS; ++s) attn[s] = lg[s] / se;
#pragma unroll
        for (int k = 0; k < 8; ++k) {
            int o = tid * 8 + k;
            int e = (o >> 4) & 63, dt2 = o & 15;
            float a = 0.f;
#pragma unroll
            for (int s = 0; s < SS; ++s)
                a += attn[s] * combL[(s * EE + e) * KK + dt2];
            wkL[o] = a;
        }
    }
    __syncthreads();   // wk ready; buf free for conv staging

    // --- conv: 4 iterations of 64-row chunks (R4 seg scheme) ---
    const int seg = tid >> 6;                    // wave-uniform
    const int r   = tid & 63;
#pragma unroll 1
    for (int it = 0; it < 4; ++it) {
        const int c2 = blockIdx.x + (it << 10);  // chunk [0,4096)
        const int be = c2 >> 5;
        const int b  = be >> 6;
        const int rowg = (c2 << 6) + r;
        const float* xr = events + (((size_t)b << 11) + (rowg & (CF - 1))) * TT;

        float wk[KK];
#pragma unroll
        for (int i = 0; i < 4; ++i) {
            float4 v = reinterpret_cast<const float4*>(wkL + be * KK)[i];
            wk[4*i] = v.x; wk[4*i+1] = v.y; wk[4*i+2] = v.z; wk[4*i+3] = v.w;
        }

        float win[32];
        if (seg == 0) {                          // t 0..15, u -8..22
#pragma unroll
            for (int k = 0; k < 8; ++k) win[k] = 0.f;
#pragma unroll
            for (int k = 0; k < 6; ++k) {
                float4 v = reinterpret_cast<const float4*>(xr)[k];
                win[8+4*k] = v.x; win[9+4*k] = v.y; win[10+4*k] = v.z; win[11+4*k] = v.w;
            }
        } else if (seg == 3) {                   // t 48..64, u 40..71
#pragma unroll
            for (int k = 0; k < 6; ++k) {
                float4 v = reinterpret_cast<const float4*>(xr + 40)[k];
                win[4*k] = v.x; win[4*k+1] = v.y; win[4*k+2] = v.z; win[4*k+3] = v.w;
            }
#pragma unroll
            for (int k = 24; k < 32; ++k) win[k] = 0.f;
        } else {                                 // seg1: u 8..39, seg2: u 24..55
            const float* bp2 = xr + (seg == 1 ? 8 : 24);
#pragma unroll
            for (int k = 0; k < 8; ++k) {
                float4 v = reinterpret_cast<const float4*>(bp2)[k];
                win[4*k] = v.x; win[4*k+1] = v.y; win[4*k+2] = v.z; win[4*k+3] = v.w;
            }
        }

        float acc[16];
#pragma unroll
        for (int i = 0; i < 16; ++i) acc[i] = 0.f;
#pragma unroll
        for (int dt = 0; dt < 16; ++dt) {
            float w = wk[dt];
#pragma unroll
            for (int i = 0; i < 16; ++i) acc[i] += w * win[i + dt];
        }
        float acc16 = 0.f;
        if (seg == 3) {
#pragma unroll
            for (int dt = 0; dt < 8; ++dt) acc16 += wk[dt] * win[16 + dt];
        }

        __syncthreads();                         // buf free (prev copy-out / prologue done)
        float* bp = buf + r * TP + seg * 16;
#pragma unroll
        for (int i = 0; i < 16; ++i) bp[i] = acc[i];
        if (seg == 3) bp[16] = acc16;
        __syncthreads();

        const float4* bs = reinterpret_cast<const float4*>(buf);
        float4* od = reinterpret_cast<float4*>(out + (size_t)c2 * (64 * TP));
        for (int j = tid; j < 64 * TP / 4; j += 256)
            od[j] = bs[j];
    }
}

extern "C" void kernel_launch(void* const* d_in, const int* in_sizes, int n_in,
                              void* d_out, int out_size, void* d_ws, size_t ws_size,
                              hipStream_t stream) {
    const float* events = (const float*)d_in[0];
    const float* tc     = (const float*)d_in[1];
    const float* tk     = (const float*)d_in[2];
    const float* w1     = (const float*)d_in[3];
    const float* b1     = (const float*)d_in[4];
    const float* w2     = (const float*)d_in[5];
    const float* b2     = (const float*)d_in[6];
    float* out = (float*)d_out;
    float* ws  = (float*)d_ws;

    hipLaunchKernelGGL(kA_gram,  dim3(64),   dim3(256), 0, stream, events, ws);
    hipLaunchKernelGGL(kB2_main, dim3(1024), dim3(256), 0, stream,
                       events, tc, tk, w1, b1, w2, b2, ws, out);
}